// Round 1
// baseline (203.359 us; speedup 1.0000x reference)
//
#include <hip/hip_runtime.h>
#include <math.h>

#define EPS 1e-7f
#define ROWP 656                 // 650 useful rows (640 outer-product + 10 bias) padded to /4
#define NETS 3
#define NROW_TOT (NETS*ROWP)     // 1968

// ---------------------------------------------------------------------------
// Kernel 1: build head-reduced hyper-weights W2r[net][row][hid]
//   row < 640 : row = h*10+kk  ->  sum_head mw[head,hid] * W2[h, col(kk)+head*64+hid]
//   640..649  : kk = row-640   ->  sum_head mw[head,hid] * b2[col(kk)+head*64+hid]
//   650..655  : zero padding
//   col(kk) = kk*256 for kk<9 (einsum weights), 2304 for kk==9 (the "+b" term, f'[9]=1)
// ---------------------------------------------------------------------------
__global__ __launch_bounds__(256) void prep_w2r(
    const float* __restrict__ W2A, const float* __restrict__ b2A,
    const float* __restrict__ W2E, const float* __restrict__ b2E,
    const float* __restrict__ W2L, const float* __restrict__ b2L,
    const float* __restrict__ merger, float* __restrict__ W2r)
{
    int idx = blockIdx.x * 256 + threadIdx.x;
    const int per_net = ROWP * 64;
    if (idx >= NETS * per_net) return;
    int net = idx / per_net;
    int r   = idx - net * per_net;
    int row = r >> 6;
    int hid = r & 63;

    // softmax of merger_w over the 4 heads, per hid
    float m0 = merger[hid], m1 = merger[64+hid], m2 = merger[128+hid], m3 = merger[192+hid];
    float mx = fmaxf(fmaxf(m0, m1), fmaxf(m2, m3));
    float e0 = expf(m0-mx), e1 = expf(m1-mx), e2 = expf(m2-mx), e3 = expf(m3-mx);
    float inv = 1.0f / (e0+e1+e2+e3);
    float w0 = e0*inv, w1 = e1*inv, w2 = e2*inv, w3 = e3*inv;

    float val = 0.0f;
    if (row < 650) {
        const float* W2 = (net==0) ? W2A : ((net==1) ? W2E : W2L);
        const float* b2 = (net==0) ? b2A : ((net==1) ? b2E : b2L);
        const float* src;
        int kk;
        if (row < 640) { int h = row / 10; kk = row - h*10; src = W2 + h*2560; }
        else           { kk = row - 640;                    src = b2; }
        int col = (kk < 9) ? kk*256 : 2304;
        val = w0*src[col+hid] + w1*src[col+64+hid] + w2*src[col+128+hid] + w3*src[col+192+hid];
    }
    W2r[idx] = val;   // idx == net*per_net + row*64 + hid
}

// ---------------------------------------------------------------------------
// Kernel 2: one block per agent (384 blocks x 256 threads). Fully fused.
// ---------------------------------------------------------------------------
__global__ __launch_bounds__(256) void agent_kernel(
    const float* __restrict__ inputs, const float* __restrict__ actions,
    const float* __restrict__ W1A, const float* __restrict__ b1A,
    const float* __restrict__ W1E, const float* __restrict__ b1E,
    const float* __restrict__ W1L, const float* __restrict__ b1L,
    const float* __restrict__ W2r,
    const float* __restrict__ fc1w, const float* __restrict__ fc1b,
    const float* __restrict__ fc2w, const float* __restrict__ fc2b,
    float* __restrict__ out_q, float* __restrict__ out_x)
{
    __shared__ float sOb[32];
    __shared__ float sSt[8], sCt[8], sSa[8], sCa[8], sVx[8], sVy[8];
    __shared__ float sRbf[8][3];
    __shared__ float sAct[3];                    // act_norm, sin_b, cos_b
    __shared__ float sF[64][10];                 // f' per pair (f'[9]=1)
    __shared__ float sH[64][64];                 // first-layer activations per pair
    __shared__ __align__(16) float sU[8 * NROW_TOT];  // U[j][net][row]
    __shared__ float sZ[8][64];                  // m_jki per j
    __shared__ float sRed[4];

    const int tid   = threadIdx.x;
    const int agent = blockIdx.x;

    // ---- load obs + action ----
    if (tid < 30) sOb[tid] = inputs[agent*30 + tid];
    if (tid == 30) sOb[30] = actions[agent*2 + 0];
    if (tid == 31) sOb[31] = actions[agent*2 + 1];
    __syncthreads();

    // ---- per-entity geometry (entities: 0-1 ally, 2-4 enemy, 5-7 landmark) ----
    if (tid < 8) {
        int e = tid;
        float px, py, vx, vy;
        if (e < 2)      {           px = sOb[10+2*e]; py = sOb[11+2*e]; vx = sOb[20+2*e]; vy = sOb[21+2*e]; }
        else if (e < 5) { int t=e-2; px = sOb[14+2*t]; py = sOb[15+2*t]; vx = sOb[24+2*t]; vy = sOb[25+2*t]; }
        else            { int t=e-5; px = sOb[4+2*t];  py = sOb[5+2*t];  vx = -sOb[0];     vy = -sOb[1]; }
        float d  = sqrtf(px*px + py*py);
        sSt[e] = py / (d + EPS);
        sCt[e] = px / (d + EPS);
        float vn = sqrtf(vx*vx + vy*vy);
        sSa[e] = vy / (vn + EPS);
        sCa[e] = vx / (vn + EPS);
        sVx[e] = vx; sVy[e] = vy;
        // rbf: offsets {0,5,10}, coeff = -0.5/25 = -0.02
        sRbf[e][0] = expf(-0.02f * d * d);
        float d5  = d - 5.0f;  sRbf[e][1] = expf(-0.02f * d5  * d5);
        float d10 = d - 10.0f; sRbf[e][2] = expf(-0.02f * d10 * d10);
    }
    if (tid == 8) {
        float ax = sOb[30], ay = sOb[31];
        float an = sqrtf(ax*ax + ay*ay);
        sAct[0] = an;
        sAct[1] = ay / (an + EPS);
        sAct[2] = ax / (an + EPS);
    }
    __syncthreads();

    // ---- pair features f'[10], pair p = j*8+k ----
    if (tid < 64) {
        int p = tid, j = p >> 3, k = p & 7;
        sF[p][0] = sRbf[k][0];
        sF[p][1] = sRbf[k][1];
        sF[p][2] = sRbf[k][2];
        sF[p][3] = sSt[k]*sCt[j] - sCt[k]*sSt[j];
        sF[p][4] = sCt[k]*sCt[j] + sSt[k]*sSt[j];
        sF[p][5] = sSa[k]*sCt[j] - sCa[k]*sSt[j];
        sF[p][6] = sCa[k]*sCt[j] + sSa[k]*sSt[j];
        sF[p][7] = sVx[k] - sVx[j];
        sF[p][8] = sVy[k] - sVy[j];
        sF[p][9] = 1.0f;
    }
    __syncthreads();

    // ---- first layer: H[p][c] = leaky_relu(f[p] @ W1_net(k) + b1), net picked by k ----
    #pragma unroll 4
    for (int i = 0; i < 16; ++i) {
        int o = i*256 + tid;
        int pair = o >> 6, c = o & 63, k = pair & 7;
        const float* W1 = (k < 2) ? W1A : ((k < 5) ? W1E : W1L);
        const float* b1 = (k < 2) ? b1A : ((k < 5) ? b1E : b1L);
        float acc = b1[c];
        #pragma unroll
        for (int kk = 0; kk < 9; ++kk) acc = fmaf(sF[pair][kk], W1[kk*64 + c], acc);
        sH[pair][c] = (acc > 0.0f) ? acc : 0.01f*acc;
    }
    __syncthreads();

    // ---- U[j][net][row]: sum over the net's k of outer(h, f') (rows<640),
    //      sum of f' (rows 640..649, bias path), zero pad (650..655) ----
    for (int e = tid; e < 8*NROW_TOT; e += 256) {
        int j   = e / NROW_TOT;
        int r   = e - j*NROW_TOT;
        int net = r / ROWP;
        int row = r - net*ROWP;
        int ks  = (net==0) ? 0 : ((net==1) ? 2 : 5);
        int kn  = (net==0) ? 2 : 3;
        float v = 0.0f;
        if (row < 640) {
            int h = row / 10, kk = row - h*10;
            for (int q = 0; q < kn; ++q) { int p = j*8 + ks + q; v = fmaf(sH[p][h], sF[p][kk], v); }
        } else if (row < 650) {
            int kk = row - 640;
            for (int q = 0; q < kn; ++q) { int p = j*8 + ks + q; v += sF[p][kk]; }
        }
        sU[e] = v;
    }
    __syncthreads();

    // ---- Z[j][hid] = sum_net U[j][net][:] @ W2r[net][:,hid] ----
    {
        int lane = tid & 63, w = tid >> 6;   // lane = hid, each wave does j = w and w+4
        const float* u0 = sU + w      * NROW_TOT;
        const float* u1 = sU + (w+4)  * NROW_TOT;
        float acc0 = 0.0f, acc1 = 0.0f;
        for (int net = 0; net < NETS; ++net) {
            const float* Wn = W2r + net * (ROWP*64);
            const float* a0 = u0 + net * ROWP;
            const float* a1 = u1 + net * ROWP;
            #pragma unroll 4
            for (int row = 0; row < ROWP; row += 4) {
                float4 x0 = *(const float4*)(a0 + row);   // ds_read_b128, wave-uniform
                float4 x1 = *(const float4*)(a1 + row);
                float wv0 = Wn[(row+0)*64 + lane];        // 256B coalesced, L2-resident
                float wv1 = Wn[(row+1)*64 + lane];
                float wv2 = Wn[(row+2)*64 + lane];
                float wv3 = Wn[(row+3)*64 + lane];
                acc0 = fmaf(x0.x, wv0, fmaf(x0.y, wv1, fmaf(x0.z, wv2, fmaf(x0.w, wv3, acc0))));
                acc1 = fmaf(x1.x, wv0, fmaf(x1.y, wv1, fmaf(x1.z, wv2, fmaf(x1.w, wv3, acc1))));
            }
        }
        sZ[w][lane]   = acc0;
        sZ[w+4][lane] = acc1;
    }
    __syncthreads();

    // ---- epilogue: final = relu([Z, an, act_angle]); x = relu(final@fc1+b); q = mean_j(x@fc2+b) ----
    {
        float an  = sAct[0], sb = sAct[1], cb = sAct[2];
        float anr = (an > 0.0f) ? an : 0.0f;
        float myq = 0.0f;
        #pragma unroll
        for (int i = 0; i < 2; ++i) {
            int o = i*256 + tid;
            int j = o >> 6, c = o & 63;
            float acc = fc1b[c];
            #pragma unroll 8
            for (int d = 0; d < 64; ++d) {
                float f = sZ[j][d];
                f = (f > 0.0f) ? f : 0.0f;
                acc = fmaf(f, fc1w[d*64 + c], acc);
            }
            float aa0 = sb*sCt[j] - cb*sSt[j];
            float aa1 = cb*sCt[j] + sb*sSt[j];
            aa0 = (aa0 > 0.0f) ? aa0 : 0.0f;
            aa1 = (aa1 > 0.0f) ? aa1 : 0.0f;
            acc = fmaf(anr, fc1w[64*64 + c], acc);
            acc = fmaf(aa0, fc1w[65*64 + c], acc);
            acc = fmaf(aa1, fc1w[66*64 + c], acc);
            float x1 = (acc > 0.0f) ? acc : 0.0f;
            out_x[(agent*8 + j)*64 + c] = x1;
            myq = fmaf(x1, fc2w[c], myq);
        }
        // block reduce for q
        for (int off = 32; off; off >>= 1) myq += __shfl_down(myq, off);
        int lane = tid & 63, w = tid >> 6;
        if (lane == 0) sRed[w] = myq;
        __syncthreads();
        if (tid == 0) out_q[agent] = (sRed[0] + sRed[1] + sRed[2] + sRed[3]) * 0.125f + fc2b[0];
    }
}

extern "C" void kernel_launch(void* const* d_in, const int* in_sizes, int n_in,
                              void* d_out, int out_size, void* d_ws, size_t ws_size,
                              hipStream_t stream) {
    const float* inputs  = (const float*)d_in[0];
    // d_in[1] = hidden_state, unused by the reference computation
    const float* actions = (const float*)d_in[2];
    const float* hA1_w = (const float*)d_in[3];  const float* hA1_b = (const float*)d_in[4];
    const float* hA2_w = (const float*)d_in[5];  const float* hA2_b = (const float*)d_in[6];
    const float* hE1_w = (const float*)d_in[7];  const float* hE1_b = (const float*)d_in[8];
    const float* hE2_w = (const float*)d_in[9];  const float* hE2_b = (const float*)d_in[10];
    const float* hL1_w = (const float*)d_in[11]; const float* hL1_b = (const float*)d_in[12];
    const float* hL2_w = (const float*)d_in[13]; const float* hL2_b = (const float*)d_in[14];
    const float* merger = (const float*)d_in[15];
    const float* fc1w = (const float*)d_in[16];  const float* fc1b = (const float*)d_in[17];
    const float* fc2w = (const float*)d_in[18];  const float* fc2b = (const float*)d_in[19];

    float* W2r = (float*)d_ws;              // 3*656*64 floats = 503,808 B
    float* q   = (float*)d_out;             // 384 floats
    float* x   = q + 384;                   // 196,608 floats

    int total = NETS * ROWP * 64;
    prep_w2r<<<(total + 255)/256, 256, 0, stream>>>(hA2_w, hA2_b, hE2_w, hE2_b,
                                                    hL2_w, hL2_b, merger, W2r);
    agent_kernel<<<384, 256, 0, stream>>>(inputs, actions,
                                          hA1_w, hA1_b, hE1_w, hE1_b, hL1_w, hL1_b,
                                          W2r, fc1w, fc1b, fc2w, fc2b, q, x);
}

// Round 2
// 128.107 us; speedup vs baseline: 1.5874x; 1.5874x over previous
//
#include <hip/hip_runtime.h>
#include <math.h>

#define EPS 1e-7f
#define ROWP 656                 // 650 useful rows (640 outer-product + 10 bias) padded to /4
#define NETS 3
#define NROW_TOT (NETS*ROWP)     // 1968
#define G4 (ROWP/4)              // 164 row-groups per net
#define PERNET (ROWP*64)         // 41984 floats per net
#define PERNET4 (G4*64)          // 10496 float4s per net

// ---------------------------------------------------------------------------
// Kernel 1: build head-reduced hyper-weights, PACKED as [net][row/4][hid][4]
// so phase-4 lane reads one float4 (4 consecutive rows for its hid).
//   row < 640 : row = h*10+kk -> sum_head mw[head,hid]*W2[h, col(kk)+head*64+hid]
//   640..649  : kk = row-640  -> sum_head mw[head,hid]*b2[col(kk)+head*64+hid]
//   650..655  : zero pad
//   col(kk) = kk*256 (kk<9), 2304 (kk==9, the "+b" einsum-bias term, f'[9]=1)
// ---------------------------------------------------------------------------
__global__ __launch_bounds__(256) void prep_w2r(
    const float* __restrict__ W2A, const float* __restrict__ b2A,
    const float* __restrict__ W2E, const float* __restrict__ b2E,
    const float* __restrict__ W2L, const float* __restrict__ b2L,
    const float* __restrict__ merger, float* __restrict__ W2r)
{
    int idx = blockIdx.x * 256 + threadIdx.x;      // one float4 per thread
    if (idx >= NETS * PERNET4) return;
    int net = idx / PERNET4;
    int rem = idx - net * PERNET4;
    int g4  = rem >> 6;
    int hid = rem & 63;

    // softmax of merger_w over the 4 heads, per hid
    float m0 = merger[hid], m1 = merger[64+hid], m2 = merger[128+hid], m3 = merger[192+hid];
    float mx = fmaxf(fmaxf(m0, m1), fmaxf(m2, m3));
    float e0 = expf(m0-mx), e1 = expf(m1-mx), e2 = expf(m2-mx), e3 = expf(m3-mx);
    float inv = 1.0f / (e0+e1+e2+e3);
    float w0 = e0*inv, w1 = e1*inv, w2 = e2*inv, w3 = e3*inv;

    const float* W2 = (net==0) ? W2A : ((net==1) ? W2E : W2L);
    const float* b2 = (net==0) ? b2A : ((net==1) ? b2E : b2L);

    float4 v;
    float* vp = &v.x;
    #pragma unroll
    for (int r = 0; r < 4; ++r) {
        int row = g4*4 + r;
        float val = 0.0f;
        if (row < 650) {
            const float* src;
            int kk;
            if (row < 640) { int h = row / 10; kk = row - h*10; src = W2 + h*2560; }
            else           { kk = row - 640;                    src = b2; }
            int col = (kk < 9) ? kk*256 : 2304;
            val = w0*src[col+hid] + w1*src[col+64+hid] + w2*src[col+128+hid] + w3*src[col+192+hid];
        }
        vp[r] = val;
    }
    ((float4*)W2r)[idx] = v;
}

// ---------------------------------------------------------------------------
// Kernel 2: one block per agent (384 blocks x 256 threads). Fully fused.
// LDS ~76 KB -> 2 blocks/CU; all 384 blocks co-resident.
// ---------------------------------------------------------------------------
__global__ __launch_bounds__(256) void agent_kernel(
    const float* __restrict__ inputs, const float* __restrict__ actions,
    const float* __restrict__ W1A, const float* __restrict__ b1A,
    const float* __restrict__ W1E, const float* __restrict__ b1E,
    const float* __restrict__ W1L, const float* __restrict__ b1L,
    const float* __restrict__ W2r,
    const float* __restrict__ fc1w, const float* __restrict__ fc1b,
    const float* __restrict__ fc2w, const float* __restrict__ fc2b,
    float* __restrict__ out_q, float* __restrict__ out_x)
{
    __shared__ float sOb[32];
    __shared__ float sSt[8], sCt[8], sSa[8], sCa[8], sVx[8], sVy[8];
    __shared__ float sRbf[8][3];
    __shared__ float sAct[3];                         // act_norm, sin_b, cos_b
    __shared__ float sF[64][10];                      // f' per pair (f'[9]=1)
    __shared__ __align__(16) float sU[8 * NROW_TOT];  // U[j][net][row]  62,976 B
    __shared__ float sZp[4][8][64];                   // per-wave Z partials 8 KB
    __shared__ float sZ[8][64];                       // relu(Z[j][hid])
    __shared__ float sRed[4];

    const int tid   = threadIdx.x;
    const int agent = blockIdx.x;

    // ---- load obs + action ----
    if (tid < 30) sOb[tid] = inputs[agent*30 + tid];
    if (tid == 30) sOb[30] = actions[agent*2 + 0];
    if (tid == 31) sOb[31] = actions[agent*2 + 1];
    __syncthreads();

    // ---- per-entity geometry (entities: 0-1 ally, 2-4 enemy, 5-7 landmark) ----
    if (tid < 8) {
        int e = tid;
        float px, py, vx, vy;
        if (e < 2)      {           px = sOb[10+2*e]; py = sOb[11+2*e]; vx = sOb[20+2*e]; vy = sOb[21+2*e]; }
        else if (e < 5) { int t=e-2; px = sOb[14+2*t]; py = sOb[15+2*t]; vx = sOb[24+2*t]; vy = sOb[25+2*t]; }
        else            { int t=e-5; px = sOb[4+2*t];  py = sOb[5+2*t];  vx = -sOb[0];     vy = -sOb[1]; }
        float d  = sqrtf(px*px + py*py);
        sSt[e] = py / (d + EPS);
        sCt[e] = px / (d + EPS);
        float vn = sqrtf(vx*vx + vy*vy);
        sSa[e] = vy / (vn + EPS);
        sCa[e] = vx / (vn + EPS);
        sVx[e] = vx; sVy[e] = vy;
        sRbf[e][0] = expf(-0.02f * d * d);
        float d5  = d - 5.0f;  sRbf[e][1] = expf(-0.02f * d5  * d5);
        float d10 = d - 10.0f; sRbf[e][2] = expf(-0.02f * d10 * d10);
    }
    if (tid == 8) {
        float ax = sOb[30], ay = sOb[31];
        float an = sqrtf(ax*ax + ay*ay);
        sAct[0] = an;
        sAct[1] = ay / (an + EPS);
        sAct[2] = ax / (an + EPS);
    }
    __syncthreads();

    // ---- pair features f'[10], pair p = j*8+k ----
    if (tid < 64) {
        int p = tid, j = p >> 3, k = p & 7;
        sF[p][0] = sRbf[k][0];
        sF[p][1] = sRbf[k][1];
        sF[p][2] = sRbf[k][2];
        sF[p][3] = sSt[k]*sCt[j] - sCt[k]*sSt[j];
        sF[p][4] = sCt[k]*sCt[j] + sSt[k]*sSt[j];
        sF[p][5] = sSa[k]*sCt[j] - sCa[k]*sSt[j];
        sF[p][6] = sCa[k]*sCt[j] + sSa[k]*sSt[j];
        sF[p][7] = sVx[k] - sVx[j];
        sF[p][8] = sVy[k] - sVy[j];
        sF[p][9] = 1.0f;
    }
    __syncthreads();

    // ---- fused layer-1 + U build ----
    // e < 1536       : (j,net,h) triple -> rows h*10+kk, kk=0..9 (recompute H here;
    //                  each H[p][h] belongs to exactly one triple, so no duplication)
    // 1536..1775     : bias rows 640+kk = sum_k f'[kk]
    // 1776..1919     : zero pad rows 650..655
    for (int e = tid; e < 1920; e += 256) {
        if (e < 1536) {
            int j = e / 192, rem = e - j*192;
            int net = rem >> 6, h = rem & 63;
            int ks = (net==0) ? 0 : ((net==1) ? 2 : 5);
            int kn = (net==0) ? 2 : 3;
            const float* W1 = (net==0) ? W1A : ((net==1) ? W1E : W1L);
            const float* b1 = (net==0) ? b1A : ((net==1) ? b1E : b1L);
            float v[10];
            #pragma unroll
            for (int kk = 0; kk < 10; ++kk) v[kk] = 0.0f;
            for (int q = 0; q < kn; ++q) {
                int p = j*8 + ks + q;
                float acc = b1[h];
                #pragma unroll
                for (int kk = 0; kk < 9; ++kk) acc = fmaf(sF[p][kk], W1[kk*64 + h], acc);
                float H = (acc > 0.0f) ? acc : 0.01f*acc;
                #pragma unroll
                for (int kk = 0; kk < 10; ++kk) v[kk] = fmaf(H, sF[p][kk], v[kk]);
            }
            float* dst = sU + j*NROW_TOT + net*ROWP + h*10;
            #pragma unroll
            for (int kk = 0; kk < 10; ++kk) dst[kk] = v[kk];
        } else if (e < 1776) {
            int t = e - 1536;
            int j = t / 30, rem = t - j*30;
            int net = rem / 10, kk = rem - net*10;
            int ks = (net==0) ? 0 : ((net==1) ? 2 : 5);
            int kn = (net==0) ? 2 : 3;
            float v = 0.0f;
            for (int q = 0; q < kn; ++q) v += sF[j*8 + ks + q][kk];
            sU[j*NROW_TOT + net*ROWP + 640 + kk] = v;
        } else {
            int t = e - 1776;
            int j = t / 18, rem = t - j*18;
            int net = rem / 6, r = rem - net*6;
            sU[j*NROW_TOT + net*ROWP + 650 + r] = 0.0f;
        }
    }
    __syncthreads();

    // ---- Z[j][hid] = sum_net U[j][net][:] @ W2r[net][:,hid] ----
    // Row-split across the 4 waves; each wave handles ALL 8 j's -> the block
    // reads W2r exactly once. lane = hid. 1 dwordx4 + 8 broadcast b128 + 32 FMA/group.
    {
        int lane = tid & 63, w = tid >> 6;
        float acc[8];
        #pragma unroll
        for (int j = 0; j < 8; ++j) acc[j] = 0.0f;
        const float4* Wp = (const float4*)W2r;
        for (int net = 0; net < NETS; ++net) {
            const float4* Wn = Wp + net*PERNET4;
            const float*  Ub = sU + net*ROWP;
            #pragma unroll 2
            for (int g = w; g < G4; g += 4) {
                float4 wv = Wn[g*64 + lane];
                int row = g*4;
                #pragma unroll
                for (int j = 0; j < 8; ++j) {
                    float4 u = *(const float4*)(Ub + j*NROW_TOT + row);
                    acc[j] = fmaf(u.x, wv.x, fmaf(u.y, wv.y, fmaf(u.z, wv.z, fmaf(u.w, wv.w, acc[j]))));
                }
            }
        }
        #pragma unroll
        for (int j = 0; j < 8; ++j) sZp[w][j][lane] = acc[j];
    }
    __syncthreads();
    for (int o = tid; o < 512; o += 256) {
        int j = o >> 6, c = o & 63;
        float z = sZp[0][j][c] + sZp[1][j][c] + sZp[2][j][c] + sZp[3][j][c];
        sZ[j][c] = (z > 0.0f) ? z : 0.0f;   // relu folded in
    }
    __syncthreads();

    // ---- epilogue: x = relu([reluZ, an, act_angle] @ fc1 + b); q = mean_j(x@fc2+b) ----
    {
        float an  = sAct[0], sb = sAct[1], cb = sAct[2];
        float anr = (an > 0.0f) ? an : 0.0f;
        float myq = 0.0f;
        #pragma unroll
        for (int i = 0; i < 2; ++i) {
            int o = i*256 + tid;
            int j = o >> 6, c = o & 63;
            float acc = fc1b[c];
            #pragma unroll 8
            for (int d = 0; d < 64; ++d)
                acc = fmaf(sZ[j][d], fc1w[d*64 + c], acc);
            float aa0 = sb*sCt[j] - cb*sSt[j];
            float aa1 = cb*sCt[j] + sb*sSt[j];
            aa0 = (aa0 > 0.0f) ? aa0 : 0.0f;
            aa1 = (aa1 > 0.0f) ? aa1 : 0.0f;
            acc = fmaf(anr, fc1w[64*64 + c], acc);
            acc = fmaf(aa0, fc1w[65*64 + c], acc);
            acc = fmaf(aa1, fc1w[66*64 + c], acc);
            float x1 = (acc > 0.0f) ? acc : 0.0f;
            out_x[(agent*8 + j)*64 + c] = x1;
            myq = fmaf(x1, fc2w[c], myq);
        }
        for (int off = 32; off; off >>= 1) myq += __shfl_down(myq, off);
        int lane = tid & 63, w = tid >> 6;
        if (lane == 0) sRed[w] = myq;
        __syncthreads();
        if (tid == 0) out_q[agent] = (sRed[0] + sRed[1] + sRed[2] + sRed[3]) * 0.125f + fc2b[0];
    }
}

extern "C" void kernel_launch(void* const* d_in, const int* in_sizes, int n_in,
                              void* d_out, int out_size, void* d_ws, size_t ws_size,
                              hipStream_t stream) {
    const float* inputs  = (const float*)d_in[0];
    // d_in[1] = hidden_state, unused by the reference computation
    const float* actions = (const float*)d_in[2];
    const float* hA1_w = (const float*)d_in[3];  const float* hA1_b = (const float*)d_in[4];
    const float* hA2_w = (const float*)d_in[5];  const float* hA2_b = (const float*)d_in[6];
    const float* hE1_w = (const float*)d_in[7];  const float* hE1_b = (const float*)d_in[8];
    const float* hE2_w = (const float*)d_in[9];  const float* hE2_b = (const float*)d_in[10];
    const float* hL1_w = (const float*)d_in[11]; const float* hL1_b = (const float*)d_in[12];
    const float* hL2_w = (const float*)d_in[13]; const float* hL2_b = (const float*)d_in[14];
    const float* merger = (const float*)d_in[15];
    const float* fc1w = (const float*)d_in[16];  const float* fc1b = (const float*)d_in[17];
    const float* fc2w = (const float*)d_in[18];  const float* fc2b = (const float*)d_in[19];

    float* W2r = (float*)d_ws;              // 3*656*64 floats = 503,808 B (packed float4)
    float* q   = (float*)d_out;             // 384 floats
    float* x   = q + 384;                   // 196,608 floats

    int total4 = NETS * PERNET4;            // 31,488 float4s
    prep_w2r<<<(total4 + 255)/256, 256, 0, stream>>>(hA2_w, hA2_b, hE2_w, hE2_b,
                                                     hL2_w, hL2_b, merger, W2r);
    agent_kernel<<<384, 256, 0, stream>>>(inputs, actions,
                                          hA1_w, hA1_b, hE1_w, hE1_b, hL1_w, hL1_b,
                                          W2r, fc1w, fc1b, fc2w, fc2b, q, x);
}

// Round 3
// 120.998 us; speedup vs baseline: 1.6807x; 1.0587x over previous
//
#include <hip/hip_runtime.h>
#include <math.h>

#define EPS 1e-7f
#define ROWP 656                 // 650 useful rows (640 outer + 10 bias) padded to /4
#define NETS 3
#define NROW_TOT (NETS*ROWP)     // 1968
#define G4 (ROWP/4)              // 164 row-groups per net (= 4 waves x 41)
#define GPW (G4/4)               // 41 groups per wave per net
#define PERNET4 (G4*64)          // 10496 float4s per net

// ---------------------------------------------------------------------------
// Kernel 1: head-reduced hyper-weights packed [net][g][hid][4rows], with row
// ordering row' = kk*64 + h (kk-major) for rows < 640 so the U-build writes
// are stride-1 (bank-conflict-free). Rows 640..649 = b2 path, 650..655 = pad.
//   col(kk) = kk*256 for kk<9, 2304 for kk==9 (the "+b" einsum term, f'[9]=1)
// ---------------------------------------------------------------------------
__global__ __launch_bounds__(256) void prep_w2r(
    const float* __restrict__ W2A, const float* __restrict__ b2A,
    const float* __restrict__ W2E, const float* __restrict__ b2E,
    const float* __restrict__ W2L, const float* __restrict__ b2L,
    const float* __restrict__ merger, float* __restrict__ W2r)
{
    int idx = blockIdx.x * 256 + threadIdx.x;      // one float4 per thread
    if (idx >= NETS * PERNET4) return;
    int net = idx / PERNET4;
    int rem = idx - net * PERNET4;
    int g4  = rem >> 6;
    int hid = rem & 63;

    float m0 = merger[hid], m1 = merger[64+hid], m2 = merger[128+hid], m3 = merger[192+hid];
    float mx = fmaxf(fmaxf(m0, m1), fmaxf(m2, m3));
    float e0 = expf(m0-mx), e1 = expf(m1-mx), e2 = expf(m2-mx), e3 = expf(m3-mx);
    float inv = 1.0f / (e0+e1+e2+e3);
    float w0 = e0*inv, w1 = e1*inv, w2 = e2*inv, w3 = e3*inv;

    const float* W2 = (net==0) ? W2A : ((net==1) ? W2E : W2L);
    const float* b2 = (net==0) ? b2A : ((net==1) ? b2E : b2L);

    float4 v;
    float* vp = &v.x;
    #pragma unroll
    for (int r = 0; r < 4; ++r) {
        int row = g4*4 + r;
        float val = 0.0f;
        if (row < 650) {
            const float* src;
            int kk;
            if (row < 640) { kk = row >> 6; int h = row & 63; src = W2 + h*2560; }
            else           { kk = row - 640;                  src = b2; }
            int col = (kk < 9) ? kk*256 : 2304;
            val = w0*src[col+hid] + w1*src[col+64+hid] + w2*src[col+128+hid] + w3*src[col+192+hid];
        }
        vp[r] = val;
    }
    ((float4*)W2r)[idx] = v;
}

// ---------------------------------------------------------------------------
// Kernel 2: one block per agent (384 x 256). LDS ~76 KB -> 2 blocks/CU.
// ---------------------------------------------------------------------------
__global__ __launch_bounds__(256, 2) void agent_kernel(
    const float* __restrict__ inputs, const float* __restrict__ actions,
    const float* __restrict__ W1A, const float* __restrict__ b1A,
    const float* __restrict__ W1E, const float* __restrict__ b1E,
    const float* __restrict__ W1L, const float* __restrict__ b1L,
    const float* __restrict__ W2r,
    const float* __restrict__ fc1w, const float* __restrict__ fc1b,
    const float* __restrict__ fc2w, const float* __restrict__ fc2b,
    float* __restrict__ out_q, float* __restrict__ out_x)
{
    __shared__ float sOb[32];
    __shared__ float sSt[8], sCt[8], sSa[8], sCa[8], sVx[8], sVy[8];
    __shared__ float sRbf[8][3];
    __shared__ float sAct[3];
    __shared__ float sF[64][10];                      // f' per pair (f'[9]=1)
    __shared__ __align__(16) float sU[8 * NROW_TOT];  // U[j][net][row'] 62,976 B
    __shared__ float sZp[4][8][64];                   // per-wave Z partials
    __shared__ float sZ[8][64];
    __shared__ float sRed[4];

    const int tid   = threadIdx.x;
    const int agent = blockIdx.x;

    if (tid < 30) sOb[tid] = inputs[agent*30 + tid];
    if (tid == 30) sOb[30] = actions[agent*2 + 0];
    if (tid == 31) sOb[31] = actions[agent*2 + 1];
    __syncthreads();

    if (tid < 8) {
        int e = tid;
        float px, py, vx, vy;
        if (e < 2)      {           px = sOb[10+2*e]; py = sOb[11+2*e]; vx = sOb[20+2*e]; vy = sOb[21+2*e]; }
        else if (e < 5) { int t=e-2; px = sOb[14+2*t]; py = sOb[15+2*t]; vx = sOb[24+2*t]; vy = sOb[25+2*t]; }
        else            { int t=e-5; px = sOb[4+2*t];  py = sOb[5+2*t];  vx = -sOb[0];     vy = -sOb[1]; }
        float d  = sqrtf(px*px + py*py);
        sSt[e] = py / (d + EPS);
        sCt[e] = px / (d + EPS);
        float vn = sqrtf(vx*vx + vy*vy);
        sSa[e] = vy / (vn + EPS);
        sCa[e] = vx / (vn + EPS);
        sVx[e] = vx; sVy[e] = vy;
        sRbf[e][0] = expf(-0.02f * d * d);
        float d5  = d - 5.0f;  sRbf[e][1] = expf(-0.02f * d5  * d5);
        float d10 = d - 10.0f; sRbf[e][2] = expf(-0.02f * d10 * d10);
    }
    if (tid == 8) {
        float ax = sOb[30], ay = sOb[31];
        float an = sqrtf(ax*ax + ay*ay);
        sAct[0] = an;
        sAct[1] = ay / (an + EPS);
        sAct[2] = ax / (an + EPS);
    }
    __syncthreads();

    if (tid < 64) {
        int p = tid, j = p >> 3, k = p & 7;
        sF[p][0] = sRbf[k][0];
        sF[p][1] = sRbf[k][1];
        sF[p][2] = sRbf[k][2];
        sF[p][3] = sSt[k]*sCt[j] - sCt[k]*sSt[j];
        sF[p][4] = sCt[k]*sCt[j] + sSt[k]*sSt[j];
        sF[p][5] = sSa[k]*sCt[j] - sCa[k]*sSt[j];
        sF[p][6] = sCa[k]*sCt[j] + sSa[k]*sSt[j];
        sF[p][7] = sVx[k] - sVx[j];
        sF[p][8] = sVy[k] - sVy[j];
        sF[p][9] = 1.0f;
    }
    __syncthreads();

    // ---- fused layer-1 + U build. Row ordering: row' = kk*64 + h ----
    // e<1536: (j,net,h) -> 10 stores at stride 64 words (conflict-free).
    for (int e = tid; e < 1920; e += 256) {
        if (e < 1536) {
            int j = e / 192, rem = e - j*192;
            int net = rem >> 6, h = rem & 63;
            int ks = (net==0) ? 0 : ((net==1) ? 2 : 5);
            int kn = (net==0) ? 2 : 3;
            const float* W1 = (net==0) ? W1A : ((net==1) ? W1E : W1L);
            const float* b1 = (net==0) ? b1A : ((net==1) ? b1E : b1L);
            float v[10];
            #pragma unroll
            for (int kk = 0; kk < 10; ++kk) v[kk] = 0.0f;
            for (int q = 0; q < kn; ++q) {
                int p = j*8 + ks + q;
                float acc = b1[h];
                #pragma unroll
                for (int kk = 0; kk < 9; ++kk) acc = fmaf(sF[p][kk], W1[kk*64 + h], acc);
                float H = (acc > 0.0f) ? acc : 0.01f*acc;
                #pragma unroll
                for (int kk = 0; kk < 10; ++kk) v[kk] = fmaf(H, sF[p][kk], v[kk]);
            }
            float* dst = sU + j*NROW_TOT + net*ROWP + h;
            #pragma unroll
            for (int kk = 0; kk < 10; ++kk) dst[kk*64] = v[kk];
        } else if (e < 1776) {
            int t = e - 1536;
            int j = t / 30, rem = t - j*30;
            int net = rem / 10, kk = rem - net*10;
            int ks = (net==0) ? 0 : ((net==1) ? 2 : 5);
            int kn = (net==0) ? 2 : 3;
            float v = 0.0f;
            for (int q = 0; q < kn; ++q) v += sF[j*8 + ks + q][kk];
            sU[j*NROW_TOT + net*ROWP + 640 + kk] = v;
        } else {
            int t = e - 1776;
            int j = t / 18, rem = t - j*18;
            int net = rem / 6, r = rem - net*6;
            sU[j*NROW_TOT + net*ROWP + 650 + r] = 0.0f;
        }
    }
    __syncthreads();

    // ---- Z contraction: lane=(q=rows-slot, hh=hid-base); acc[8j][4hid] ----
    // One ds_read_b128 serves 4 distinct row-groups (q); global dwordx4 fully
    // lane-distinct. Rows split 4-way across waves; q-reduce via shfl_xor.
    {
        const int lane = tid & 63, w = tid >> 6;
        const int q = lane >> 4, hh = lane & 15;
        float acc[8][4];
        #pragma unroll
        for (int j = 0; j < 8; ++j)
            #pragma unroll
            for (int k = 0; k < 4; ++k) acc[j][k] = 0.0f;

        const float4* Wp = (const float4*)W2r;
        const int base = w * GPW;                 // this wave's group range per net
        for (int net = 0; net < NETS; ++net) {
            const float4* Wn = Wp + net*PERNET4;
            const float*  Ub = sU + net*ROWP;
            #pragma unroll 2
            for (int u = 0; u < 10; ++u) {        // 40 full groups (u*4+q <= 39)
                int g = base + u*4 + q;
                const float4* wb = Wn + g*64 + hh;
                float4 wk0 = wb[0], wk1 = wb[16], wk2 = wb[32], wk3 = wb[48];
                float4 uj[8];
                #pragma unroll
                for (int j = 0; j < 8; ++j) uj[j] = *(const float4*)(Ub + j*NROW_TOT + g*4);
                #pragma unroll
                for (int j = 0; j < 8; ++j) {
                    float4 uu = uj[j];
                    acc[j][0] = fmaf(uu.x,wk0.x, fmaf(uu.y,wk0.y, fmaf(uu.z,wk0.z, fmaf(uu.w,wk0.w, acc[j][0]))));
                    acc[j][1] = fmaf(uu.x,wk1.x, fmaf(uu.y,wk1.y, fmaf(uu.z,wk1.z, fmaf(uu.w,wk1.w, acc[j][1]))));
                    acc[j][2] = fmaf(uu.x,wk2.x, fmaf(uu.y,wk2.y, fmaf(uu.z,wk2.z, fmaf(uu.w,wk2.w, acc[j][2]))));
                    acc[j][3] = fmaf(uu.x,wk3.x, fmaf(uu.y,wk3.y, fmaf(uu.z,wk3.z, fmaf(uu.w,wk3.w, acc[j][3]))));
                }
            }
            // tail group (index base+40), only q==0 lanes
            if (q == 0) {
                int g = base + 40;
                const float4* wb = Wn + g*64 + hh;
                float4 wk0 = wb[0], wk1 = wb[16], wk2 = wb[32], wk3 = wb[48];
                #pragma unroll
                for (int j = 0; j < 8; ++j) {
                    float4 uu = *(const float4*)(Ub + j*NROW_TOT + g*4);
                    acc[j][0] = fmaf(uu.x,wk0.x, fmaf(uu.y,wk0.y, fmaf(uu.z,wk0.z, fmaf(uu.w,wk0.w, acc[j][0]))));
                    acc[j][1] = fmaf(uu.x,wk1.x, fmaf(uu.y,wk1.y, fmaf(uu.z,wk1.z, fmaf(uu.w,wk1.w, acc[j][1]))));
                    acc[j][2] = fmaf(uu.x,wk2.x, fmaf(uu.y,wk2.y, fmaf(uu.z,wk2.z, fmaf(uu.w,wk2.w, acc[j][2]))));
                    acc[j][3] = fmaf(uu.x,wk3.x, fmaf(uu.y,wk3.y, fmaf(uu.z,wk3.z, fmaf(uu.w,wk3.w, acc[j][3]))));
                }
            }
        }
        // reduce over q (lanes ^16, ^32), then q==0 lanes hold the wave total
        #pragma unroll
        for (int j = 0; j < 8; ++j) {
            #pragma unroll
            for (int k = 0; k < 4; ++k) {
                float v = acc[j][k];
                v += __shfl_xor(v, 16);
                v += __shfl_xor(v, 32);
                if (q == 0) sZp[w][j][k*16 + hh] = v;
            }
        }
    }
    __syncthreads();
    for (int o = tid; o < 512; o += 256) {
        int j = o >> 6, c = o & 63;
        float z = sZp[0][j][c] + sZp[1][j][c] + sZp[2][j][c] + sZp[3][j][c];
        sZ[j][c] = (z > 0.0f) ? z : 0.0f;   // relu folded in
    }
    __syncthreads();

    // ---- epilogue ----
    {
        float an  = sAct[0], sb = sAct[1], cb = sAct[2];
        float anr = (an > 0.0f) ? an : 0.0f;
        float myq = 0.0f;
        #pragma unroll
        for (int i = 0; i < 2; ++i) {
            int o = i*256 + tid;
            int j = o >> 6, c = o & 63;
            float acc = fc1b[c];
            #pragma unroll 8
            for (int d = 0; d < 64; ++d)
                acc = fmaf(sZ[j][d], fc1w[d*64 + c], acc);
            float aa0 = sb*sCt[j] - cb*sSt[j];
            float aa1 = cb*sCt[j] + sb*sSt[j];
            aa0 = (aa0 > 0.0f) ? aa0 : 0.0f;
            aa1 = (aa1 > 0.0f) ? aa1 : 0.0f;
            acc = fmaf(anr, fc1w[64*64 + c], acc);
            acc = fmaf(aa0, fc1w[65*64 + c], acc);
            acc = fmaf(aa1, fc1w[66*64 + c], acc);
            float x1 = (acc > 0.0f) ? acc : 0.0f;
            out_x[(agent*8 + j)*64 + c] = x1;
            myq = fmaf(x1, fc2w[c], myq);
        }
        for (int off = 32; off; off >>= 1) myq += __shfl_down(myq, off);
        int lane = tid & 63, w = tid >> 6;
        if (lane == 0) sRed[w] = myq;
        __syncthreads();
        if (tid == 0) out_q[agent] = (sRed[0] + sRed[1] + sRed[2] + sRed[3]) * 0.125f + fc2b[0];
    }
}

extern "C" void kernel_launch(void* const* d_in, const int* in_sizes, int n_in,
                              void* d_out, int out_size, void* d_ws, size_t ws_size,
                              hipStream_t stream) {
    const float* inputs  = (const float*)d_in[0];
    const float* actions = (const float*)d_in[2];
    const float* hA1_w = (const float*)d_in[3];  const float* hA1_b = (const float*)d_in[4];
    const float* hA2_w = (const float*)d_in[5];  const float* hA2_b = (const float*)d_in[6];
    const float* hE1_w = (const float*)d_in[7];  const float* hE1_b = (const float*)d_in[8];
    const float* hE2_w = (const float*)d_in[9];  const float* hE2_b = (const float*)d_in[10];
    const float* hL1_w = (const float*)d_in[11]; const float* hL1_b = (const float*)d_in[12];
    const float* hL2_w = (const float*)d_in[13]; const float* hL2_b = (const float*)d_in[14];
    const float* merger = (const float*)d_in[15];
    const float* fc1w = (const float*)d_in[16];  const float* fc1b = (const float*)d_in[17];
    const float* fc2w = (const float*)d_in[18];  const float* fc2b = (const float*)d_in[19];

    float* W2r = (float*)d_ws;              // 3*656*64 floats, packed [net][g][hid][4]
    float* q   = (float*)d_out;             // 384 floats
    float* x   = q + 384;                   // 196,608 floats

    int total4 = NETS * PERNET4;            // 31,488 float4s
    prep_w2r<<<(total4 + 255)/256, 256, 0, stream>>>(hA2_w, hA2_b, hE2_w, hE2_b,
                                                     hL2_w, hL2_b, merger, W2r);
    agent_kernel<<<384, 256, 0, stream>>>(inputs, actions,
                                          hA1_w, hA1_b, hE1_w, hE1_b, hL1_w, hL1_b,
                                          W2r, fc1w, fc1b, fc2w, fc2b, q, x);
}